// Round 1
// baseline (1949.550 us; speedup 1.0000x reference)
//
#include <hip/hip_runtime.h>

typedef unsigned short u16;
typedef __bf16 bf16x8 __attribute__((ext_vector_type(8)));
typedef float f32x4 __attribute__((ext_vector_type(4)));

#define E_ 1024
#define T_ 2048
#define B_ 2
#define H_ 16
#define FF_ 4096
#define M_ 4096   // B*T

__device__ __forceinline__ u16 f2b(float f) {
    union { float f; unsigned u; } c; c.f = f;
    unsigned r = c.u + 0x7FFFu + ((c.u >> 16) & 1u);
    return (u16)(r >> 16);
}

// ---------------- fp32 -> bf16 convert (vectorized) ----------------
__global__ void cvt_bf16(u16* __restrict__ dst, const float* __restrict__ src, int n4) {
    int i = blockIdx.x * blockDim.x + threadIdx.x;
    if (i < n4) {
        float4 f = *(const float4*)&src[i * 4];
        ushort4 o;
        o.x = f2b(f.x); o.y = f2b(f.y); o.z = f2b(f.z); o.w = f2b(f.w);
        *(ushort4*)&dst[i * 4] = o;
    }
}

// ---------------- small fp32 copy (bias concat) ----------------
__global__ void copyf(float* __restrict__ dst, const float* __restrict__ src, int n) {
    int i = blockIdx.x * blockDim.x + threadIdx.x;
    if (i < n) dst[i] = src[i];
}

// ---------------- LayerNorm: 1 wave per row of 1024 ----------------
__global__ __launch_bounds__(64) void ln_fwd(u16* __restrict__ out, const float* __restrict__ x,
                                             const float* __restrict__ g, const float* __restrict__ bta) {
    int row = blockIdx.x;
    int t = threadIdx.x;
    const float* xr = x + (size_t)row * E_;
    float v[16];
    float sum = 0.f, ss = 0.f;
#pragma unroll
    for (int c = 0; c < 4; c++) {
        float4 f = *(const float4*)&xr[c * 256 + t * 4];
        v[c * 4 + 0] = f.x; v[c * 4 + 1] = f.y; v[c * 4 + 2] = f.z; v[c * 4 + 3] = f.w;
        sum += f.x + f.y + f.z + f.w;
        ss += f.x * f.x + f.y * f.y + f.z * f.z + f.w * f.w;
    }
#pragma unroll
    for (int d = 32; d; d >>= 1) {
        sum += __shfl_xor(sum, d);
        ss  += __shfl_xor(ss, d);
    }
    float mu = sum * (1.f / E_);
    float var = ss * (1.f / E_) - mu * mu;
    float rs = rsqrtf(var + 1e-5f);
#pragma unroll
    for (int c = 0; c < 4; c++) {
        int idx = c * 256 + t * 4;
        float4 g4 = *(const float4*)&g[idx];
        float4 b4 = *(const float4*)&bta[idx];
        ushort4 o;
        o.x = f2b((v[c * 4 + 0] - mu) * rs * g4.x + b4.x);
        o.y = f2b((v[c * 4 + 1] - mu) * rs * g4.y + b4.y);
        o.z = f2b((v[c * 4 + 2] - mu) * rs * g4.z + b4.z);
        o.w = f2b((v[c * 4 + 3] - mu) * rs * g4.w + b4.w);
        *(ushort4*)&out[(size_t)row * E_ + idx] = o;
    }
}

// ---------------- bf16 MFMA GEMM: C[M,N] = A[M,K] * Bt[N,K]^T + bias (+res)(relu) ----------------
// 128x128 tile, 256 threads (4 waves 2x2), BK=32, mfma_f32_16x16x32_bf16.
#define LDSS 40  // padded lds stride (bf16 elems) to break bank conflicts
__global__ __launch_bounds__(256) void gemm_bt(
        const u16* __restrict__ A, const u16* __restrict__ Bt,
        const float* __restrict__ bias, const float* __restrict__ residual,
        float* __restrict__ outF, u16* __restrict__ outB,
        int M, int N, int K, int relu) {
    __shared__ u16 As[128 * LDSS];
    __shared__ u16 Bs[128 * LDSS];
    int tid = threadIdx.x;
    int m0 = blockIdx.y * 128, n0 = blockIdx.x * 128;
    int wave = tid >> 6, lane = tid & 63;
    int wm = wave & 1, wn = wave >> 1;
    int r16 = lane & 15, kg = lane >> 4;

    f32x4 acc[4][4] = {};

    int arow = tid >> 2;           // 0..63
    int ak8 = (tid & 3) * 8;       // 0,8,16,24

    for (int k0 = 0; k0 < K; k0 += 32) {
        uint4 a0 = *(const uint4*)&A[(size_t)(m0 + arow) * K + k0 + ak8];
        uint4 a1 = *(const uint4*)&A[(size_t)(m0 + arow + 64) * K + k0 + ak8];
        uint4 b0 = *(const uint4*)&Bt[(size_t)(n0 + arow) * K + k0 + ak8];
        uint4 b1 = *(const uint4*)&Bt[(size_t)(n0 + arow + 64) * K + k0 + ak8];
        __syncthreads();
        *(uint4*)&As[arow * LDSS + ak8] = a0;
        *(uint4*)&As[(arow + 64) * LDSS + ak8] = a1;
        *(uint4*)&Bs[arow * LDSS + ak8] = b0;
        *(uint4*)&Bs[(arow + 64) * LDSS + ak8] = b1;
        __syncthreads();

        bf16x8 af[4], bfr[4];
#pragma unroll
        for (int mt = 0; mt < 4; mt++)
            af[mt] = *(const bf16x8*)&As[(wm * 64 + mt * 16 + r16) * LDSS + kg * 8];
#pragma unroll
        for (int nt = 0; nt < 4; nt++)
            bfr[nt] = *(const bf16x8*)&Bs[(wn * 64 + nt * 16 + r16) * LDSS + kg * 8];
#pragma unroll
        for (int mt = 0; mt < 4; mt++)
#pragma unroll
            for (int nt = 0; nt < 4; nt++)
                acc[mt][nt] = __builtin_amdgcn_mfma_f32_16x16x32_bf16(af[mt], bfr[nt], acc[mt][nt], 0, 0, 0);
    }

#pragma unroll
    for (int mt = 0; mt < 4; mt++) {
#pragma unroll
        for (int nt = 0; nt < 4; nt++) {
            int gm = m0 + wm * 64 + mt * 16 + kg * 4;
            int gn = n0 + wn * 64 + nt * 16 + r16;
            float bv = bias[gn];
#pragma unroll
            for (int r = 0; r < 4; r++) {
                float v = acc[mt][nt][r] + bv;
                size_t off = (size_t)(gm + r) * N + gn;
                if (residual) v += residual[off];
                if (relu) v = fmaxf(v, 0.f);
                if (outF) outF[off] = v;
                else outB[off] = f2b(v);
            }
        }
    }
}

// ---------------- causal attention, fp32, online softmax ----------------
// grid.x = B*H*(T/256); block = 256 threads, 1 q-row per thread.
// qkv layout: [B*T, 3072], q cols 0..1023 (h*64+d), k +1024, v +2048.
__global__ __launch_bounds__(256) void attn_fwd(const float* __restrict__ qkv, u16* __restrict__ out) {
    __shared__ float kt[32 * 64];
    __shared__ float vt[32 * 64];
    __shared__ float sS[32 * 257];

    int bz = blockIdx.x;
    int qb = bz & 7;
    int h = (bz >> 3) & 15;
    int b = bz >> 7;
    int tid = threadIdx.x;
    int tq = qb * 256 + tid;

    size_t rowQ = ((size_t)(b * T_ + tq)) * 3072 + h * 64;
    float q[64];
#pragma unroll
    for (int c = 0; c < 16; c++) {
        float4 f = *(const float4*)&qkv[rowQ + c * 4];
        q[c * 4 + 0] = f.x * 0.125f; q[c * 4 + 1] = f.y * 0.125f;
        q[c * 4 + 2] = f.z * 0.125f; q[c * 4 + 3] = f.w * 0.125f;
    }
    float o[64];
#pragma unroll
    for (int d = 0; d < 64; d++) o[d] = 0.f;
    float mrun = -INFINITY, lrun = 0.f;

    int ntile = (qb + 1) * 8;  // tiles of 32 keys
    for (int t = 0; t < ntile; t++) {
        int j0 = t * 32;
        __syncthreads();
#pragma unroll
        for (int i = 0; i < 2; i++) {
            int idx = tid + i * 256;          // 0..511
            int r = idx >> 4, c4 = (idx & 15) * 4;
            size_t gbase = ((size_t)(b * T_ + j0 + r)) * 3072 + 1024 + h * 64 + c4;
            *(float4*)&kt[r * 64 + c4] = *(const float4*)&qkv[gbase];
            *(float4*)&vt[r * 64 + c4] = *(const float4*)&qkv[gbase + 1024];
        }
        __syncthreads();

        float tmax = -INFINITY;
        for (int jj = 0; jj < 32; jj++) {
            float s = 0.f;
#pragma unroll
            for (int c = 0; c < 16; c++) {
                float4 k4 = *(const float4*)&kt[jj * 64 + c * 4];
                s += q[c * 4 + 0] * k4.x + q[c * 4 + 1] * k4.y
                   + q[c * 4 + 2] * k4.z + q[c * 4 + 3] * k4.w;
            }
            s = (j0 + jj <= tq) ? s : -INFINITY;
            sS[jj * 257 + tid] = s;
            tmax = fmaxf(tmax, s);
        }

        float mnew = fmaxf(mrun, tmax);
        float alpha = __expf(mrun - mnew);   // exp(-inf)=0 on first tile
        lrun *= alpha;
#pragma unroll
        for (int d = 0; d < 64; d++) o[d] *= alpha;

        for (int jj = 0; jj < 32; jj++) {
            float p = __expf(sS[jj * 257 + tid] - mnew);  // masked -> exp(-inf)=0
            lrun += p;
#pragma unroll
            for (int c = 0; c < 16; c++) {
                float4 v4 = *(const float4*)&vt[jj * 64 + c * 4];
                o[c * 4 + 0] += p * v4.x; o[c * 4 + 1] += p * v4.y;
                o[c * 4 + 2] += p * v4.z; o[c * 4 + 3] += p * v4.w;
            }
        }
        mrun = mnew;
    }

    float inv = 1.f / lrun;
    size_t orow = ((size_t)(b * T_ + tq)) * E_ + h * 64;
#pragma unroll
    for (int c = 0; c < 16; c++) {
        ushort4 ov;
        ov.x = f2b(o[c * 4 + 0] * inv); ov.y = f2b(o[c * 4 + 1] * inv);
        ov.z = f2b(o[c * 4 + 2] * inv); ov.w = f2b(o[c * 4 + 3] * inv);
        *(ushort4*)&out[orow + c * 4] = ov;
    }
}

extern "C" void kernel_launch(void* const* d_in, const int* in_sizes, int n_in,
                              void* d_out, int out_size, void* d_ws, size_t ws_size,
                              hipStream_t stream) {
    const float* x    = (const float*)d_in[0];
    const float* Wq   = (const float*)d_in[1];
    const float* bq   = (const float*)d_in[2];
    const float* Wk   = (const float*)d_in[3];
    const float* bk   = (const float*)d_in[4];
    const float* Wv   = (const float*)d_in[5];
    const float* bv   = (const float*)d_in[6];
    const float* Wo   = (const float*)d_in[7];
    const float* bo   = (const float*)d_in[8];
    const float* W1   = (const float*)d_in[9];
    const float* b1   = (const float*)d_in[10];
    const float* W2   = (const float*)d_in[11];
    const float* b2   = (const float*)d_in[12];
    const float* ln1g = (const float*)d_in[13];
    const float* ln1b = (const float*)d_in[14];
    const float* ln2g = (const float*)d_in[15];
    const float* ln2b = (const float*)d_in[16];

    char* ws = (char*)d_ws;
    size_t off = 0;
    auto alloc = [&](size_t bytes) { char* p = ws + off; off += (bytes + 255) & ~(size_t)255; return p; };

    u16*   hB    = (u16*)  alloc((size_t)M_ * E_ * 2);        // LN1 out bf16
    u16*   WqkvB = (u16*)  alloc((size_t)3 * E_ * E_ * 2);    // packed qkv weights bf16
    u16*   WoB   = (u16*)  alloc((size_t)E_ * E_ * 2);
    u16*   W1B   = (u16*)  alloc((size_t)FF_ * E_ * 2);
    u16*   W2B   = (u16*)  alloc((size_t)E_ * FF_ * 2);
    float* bqkv  = (float*)alloc(3 * E_ * 4);
    float* qkv   = (float*)alloc((size_t)M_ * 3 * E_ * 4);    // fp32 qkv
    u16*   attnB = (u16*)  alloc((size_t)M_ * E_ * 2);        // attention out bf16
    float* x2    = (float*)alloc((size_t)M_ * E_ * 4);        // after out-proj + residual
    u16*   h2B   = (u16*)  alloc((size_t)M_ * E_ * 2);        // LN2 out bf16
    u16*   rB    = (u16*)  alloc((size_t)M_ * FF_ * 2);       // relu(ff1) bf16

    // weight conversions
    int nW = E_ * E_ / 4;   // 262144 float4s
    cvt_bf16<<<(nW + 255) / 256, 256, 0, stream>>>(WqkvB,                 Wq, nW);
    cvt_bf16<<<(nW + 255) / 256, 256, 0, stream>>>(WqkvB + E_ * E_,       Wk, nW);
    cvt_bf16<<<(nW + 255) / 256, 256, 0, stream>>>(WqkvB + 2 * E_ * E_,   Wv, nW);
    cvt_bf16<<<(nW + 255) / 256, 256, 0, stream>>>(WoB, Wo, nW);
    int nW1 = FF_ * E_ / 4;
    cvt_bf16<<<(nW1 + 255) / 256, 256, 0, stream>>>(W1B, W1, nW1);
    cvt_bf16<<<(nW1 + 255) / 256, 256, 0, stream>>>(W2B, W2, nW1);
    copyf<<<4, 256, 0, stream>>>(bqkv,           bq, E_);
    copyf<<<4, 256, 0, stream>>>(bqkv + E_,      bk, E_);
    copyf<<<4, 256, 0, stream>>>(bqkv + 2 * E_,  bv, E_);

    // LN1
    ln_fwd<<<M_, 64, 0, stream>>>(hB, x, ln1g, ln1b);

    // QKV projection: [4096,1024] x [3072,1024]^T -> [4096,3072]
    gemm_bt<<<dim3(3 * E_ / 128, M_ / 128), 256, 0, stream>>>(
        hB, WqkvB, bqkv, nullptr, qkv, nullptr, M_, 3 * E_, E_, 0);

    // attention
    attn_fwd<<<B_ * H_ * (T_ / 256), 256, 0, stream>>>(qkv, attnB);

    // out projection + residual: x2 = x + attn @ Wo^T + bo
    gemm_bt<<<dim3(E_ / 128, M_ / 128), 256, 0, stream>>>(
        attnB, WoB, bo, x, x2, nullptr, M_, E_, E_, 0);

    // LN2
    ln_fwd<<<M_, 64, 0, stream>>>(h2B, x2, ln2g, ln2b);

    // FF1 + relu -> bf16
    gemm_bt<<<dim3(FF_ / 128, M_ / 128), 256, 0, stream>>>(
        h2B, W1B, b1, nullptr, nullptr, rB, M_, FF_, E_, 1);

    // FF2 + residual -> out
    gemm_bt<<<dim3(E_ / 128, M_ / 128), 256, 0, stream>>>(
        rB, W2B, b2, x2, (float*)d_out, nullptr, M_, E_, FF_, 0);
}

// Round 2
// 596.137 us; speedup vs baseline: 3.2703x; 3.2703x over previous
//
#include <hip/hip_runtime.h>

typedef unsigned short u16;
typedef __bf16 bf16x8 __attribute__((ext_vector_type(8)));
typedef float f32x4 __attribute__((ext_vector_type(4)));

#define E_ 1024
#define T_ 2048
#define B_ 2
#define H_ 16
#define FF_ 4096
#define M_ 4096   // B*T

__device__ __forceinline__ u16 f2b(float f) {
    union { float f; unsigned u; } c; c.f = f;
    unsigned r = c.u + 0x7FFFu + ((c.u >> 16) & 1u);
    return (u16)(r >> 16);
}

// ---------------- fp32 -> bf16 convert (vectorized) ----------------
__global__ void cvt_bf16(u16* __restrict__ dst, const float* __restrict__ src, int n4) {
    int i = blockIdx.x * blockDim.x + threadIdx.x;
    if (i < n4) {
        float4 f = *(const float4*)&src[i * 4];
        ushort4 o;
        o.x = f2b(f.x); o.y = f2b(f.y); o.z = f2b(f.z); o.w = f2b(f.w);
        *(ushort4*)&dst[i * 4] = o;
    }
}

// ---------------- small fp32 copy (bias concat) ----------------
__global__ void copyf(float* __restrict__ dst, const float* __restrict__ src, int n) {
    int i = blockIdx.x * blockDim.x + threadIdx.x;
    if (i < n) dst[i] = src[i];
}

// ---------------- LayerNorm: 1 wave per row of 1024 ----------------
__global__ __launch_bounds__(64) void ln_fwd(u16* __restrict__ out, const float* __restrict__ x,
                                             const float* __restrict__ g, const float* __restrict__ bta) {
    int row = blockIdx.x;
    int t = threadIdx.x;
    const float* xr = x + (size_t)row * E_;
    float v[16];
    float sum = 0.f, ss = 0.f;
#pragma unroll
    for (int c = 0; c < 4; c++) {
        float4 f = *(const float4*)&xr[c * 256 + t * 4];
        v[c * 4 + 0] = f.x; v[c * 4 + 1] = f.y; v[c * 4 + 2] = f.z; v[c * 4 + 3] = f.w;
        sum += f.x + f.y + f.z + f.w;
        ss += f.x * f.x + f.y * f.y + f.z * f.z + f.w * f.w;
    }
#pragma unroll
    for (int d = 32; d; d >>= 1) {
        sum += __shfl_xor(sum, d);
        ss  += __shfl_xor(ss, d);
    }
    float mu = sum * (1.f / E_);
    float var = ss * (1.f / E_) - mu * mu;
    float rs = rsqrtf(var + 1e-5f);
#pragma unroll
    for (int c = 0; c < 4; c++) {
        int idx = c * 256 + t * 4;
        float4 g4 = *(const float4*)&g[idx];
        float4 b4 = *(const float4*)&bta[idx];
        ushort4 o;
        o.x = f2b((v[c * 4 + 0] - mu) * rs * g4.x + b4.x);
        o.y = f2b((v[c * 4 + 1] - mu) * rs * g4.y + b4.y);
        o.z = f2b((v[c * 4 + 2] - mu) * rs * g4.z + b4.z);
        o.w = f2b((v[c * 4 + 3] - mu) * rs * g4.w + b4.w);
        *(ushort4*)&out[(size_t)row * E_ + idx] = o;
    }
}

// ---------------- bf16 MFMA GEMM: C[M,N] = A[M,K] * Bt[N,K]^T + bias (+res)(relu) ----------------
// 128x128 tile, 256 threads (4 waves 2x2), BK=32, mfma_f32_16x16x32_bf16.
// qscale: multiply cols gn<1024 by 0.125 (Q prescale for attention).
// vtmode: write bf16 TRANSPOSED as [b*1024+gn][t] (t = gm%2048, b = gm/2048), for V.
#define LDSS 40  // padded lds stride (bf16 elems)
__global__ __launch_bounds__(256) void gemm_bt(
        const u16* __restrict__ A, const u16* __restrict__ Bt,
        const float* __restrict__ bias, const float* __restrict__ residual,
        float* __restrict__ outF, u16* __restrict__ outB,
        int M, int N, int K, int relu, int qscale, int vtmode) {
    __shared__ u16 As[128 * LDSS];
    __shared__ u16 Bs[128 * LDSS];
    int tid = threadIdx.x;
    int m0 = blockIdx.y * 128, n0 = blockIdx.x * 128;
    int wave = tid >> 6, lane = tid & 63;
    int wm = wave & 1, wn = wave >> 1;
    int r16 = lane & 15, kg = lane >> 4;

    f32x4 acc[4][4] = {};

    int arow = tid >> 2;           // 0..63
    int ak8 = (tid & 3) * 8;       // 0,8,16,24

    for (int k0 = 0; k0 < K; k0 += 32) {
        uint4 a0 = *(const uint4*)&A[(size_t)(m0 + arow) * K + k0 + ak8];
        uint4 a1 = *(const uint4*)&A[(size_t)(m0 + arow + 64) * K + k0 + ak8];
        uint4 b0 = *(const uint4*)&Bt[(size_t)(n0 + arow) * K + k0 + ak8];
        uint4 b1 = *(const uint4*)&Bt[(size_t)(n0 + arow + 64) * K + k0 + ak8];
        __syncthreads();
        *(uint4*)&As[arow * LDSS + ak8] = a0;
        *(uint4*)&As[(arow + 64) * LDSS + ak8] = a1;
        *(uint4*)&Bs[arow * LDSS + ak8] = b0;
        *(uint4*)&Bs[(arow + 64) * LDSS + ak8] = b1;
        __syncthreads();

        bf16x8 af[4], bfr[4];
#pragma unroll
        for (int mt = 0; mt < 4; mt++)
            af[mt] = *(const bf16x8*)&As[(wm * 64 + mt * 16 + r16) * LDSS + kg * 8];
#pragma unroll
        for (int nt = 0; nt < 4; nt++)
            bfr[nt] = *(const bf16x8*)&Bs[(wn * 64 + nt * 16 + r16) * LDSS + kg * 8];
#pragma unroll
        for (int mt = 0; mt < 4; mt++)
#pragma unroll
            for (int nt = 0; nt < 4; nt++)
                acc[mt][nt] = __builtin_amdgcn_mfma_f32_16x16x32_bf16(af[mt], bfr[nt], acc[mt][nt], 0, 0, 0);
    }

#pragma unroll
    for (int mt = 0; mt < 4; mt++) {
#pragma unroll
        for (int nt = 0; nt < 4; nt++) {
            int gm = m0 + wm * 64 + mt * 16 + kg * 4;
            int gn = n0 + wn * 64 + nt * 16 + r16;
            float bv = bias[gn];
            if (vtmode) {
                // V path: out[(b*1024+gn)*2048 + t..t+3], regs are consecutive t
                int bq = gm >> 11, tq = gm & 2047;
                ushort4 ov;
                ov.x = f2b(acc[mt][nt][0] + bv);
                ov.y = f2b(acc[mt][nt][1] + bv);
                ov.z = f2b(acc[mt][nt][2] + bv);
                ov.w = f2b(acc[mt][nt][3] + bv);
                *(ushort4*)&outB[((size_t)(bq * 1024 + gn)) * 2048 + tq] = ov;
            } else {
                float scl = (qscale && gn < 1024) ? 0.125f : 1.0f;
#pragma unroll
                for (int r = 0; r < 4; r++) {
                    float v = (acc[mt][nt][r] + bv) * scl;
                    size_t off = (size_t)(gm + r) * N + gn;
                    if (residual) v += residual[off];
                    if (relu) v = fmaxf(v, 0.f);
                    if (outF) outF[off] = v;
                    else outB[off] = f2b(v);
                }
            }
        }
    }
}

// ---------------- MFMA flash attention (bf16, causal) ----------------
// grid = B*H*(T/64); 256 threads = 4 waves, 16 q-rows per wave.
// qk: [M, 2048] bf16 (cols 0..1023 = Q prescaled by 0.125, 1024..2047 = K)
// vt: [B*1024, 2048] bf16 = V transposed: [(b*1024 + h*64 + d)][t]
// out: [M, 1024] bf16
#define AST 88   // LDS row stride (u16): 176B, 16B-aligned, 8-row bank spread
__global__ __launch_bounds__(256) void attn_mfma(
        const u16* __restrict__ qk, const u16* __restrict__ vt,
        u16* __restrict__ out) {
    __shared__ u16 Ks[64 * AST];       // K[key][d]
    __shared__ u16 Vs[64 * AST];       // Vt[d][key]
    __shared__ u16 Ps[4][16 * AST];    // per-wave P[q][key]

    int bz = blockIdx.x;
    int qt = bz & 31;
    int h  = (bz >> 5) & 15;
    int b  = bz >> 9;

    int tid = threadIdx.x;
    int w = tid >> 6, lane = tid & 63;
    int g = lane >> 4, l16 = lane & 15;

    // Q fragments (A-layout: m=l16, k=g*8+j), Q already prescaled by 0.125
    int qrow = qt * 64 + w * 16 + l16;
    bf16x8 qf[2];
    qf[0] = *(const bf16x8*)&qk[(size_t)(b * T_ + qrow) * 2048 + h * 64 + g * 8];
    qf[1] = *(const bf16x8*)&qk[(size_t)(b * T_ + qrow) * 2048 + h * 64 + 32 + g * 8];

    f32x4 o[4] = {};                    // O frags: q=g*4+r, d=nt*16+l16
    float mrun[4] = {-INFINITY, -INFINITY, -INFINITY, -INFINITY};
    float lrun[4] = {0.f, 0.f, 0.f, 0.f};

    for (int t = 0; t <= qt; t++) {
        int j0 = t * 64;
        __syncthreads();
#pragma unroll
        for (int i = 0; i < 2; i++) {   // stage K tile: 64 keys x 64 d
            int c = tid + i * 256;
            int row = c >> 3, d8 = (c & 7) * 8;
            *(uint4*)&Ks[row * AST + d8] =
                *(const uint4*)&qk[(size_t)(b * T_ + j0 + row) * 2048 + 1024 + h * 64 + d8];
        }
#pragma unroll
        for (int i = 0; i < 2; i++) {   // stage Vt tile: 64 d x 64 keys
            int c = tid + i * 256;
            int d = c >> 3, k8 = (c & 7) * 8;
            *(uint4*)&Vs[d * AST + k8] =
                *(const uint4*)&vt[(size_t)(b * 1024 + h * 64 + d) * 2048 + j0 + k8];
        }
        __syncthreads();

        // S = Q K^T  (C-layout: q = g*4+r, key = nt*16+l16)
        f32x4 s[4] = {};
#pragma unroll
        for (int nt = 0; nt < 4; nt++) {
            bf16x8 k0 = *(const bf16x8*)&Ks[(nt * 16 + l16) * AST + g * 8];
            bf16x8 k1 = *(const bf16x8*)&Ks[(nt * 16 + l16) * AST + 32 + g * 8];
            s[nt] = __builtin_amdgcn_mfma_f32_16x16x32_bf16(qf[0], k0, s[nt], 0, 0, 0);
            s[nt] = __builtin_amdgcn_mfma_f32_16x16x32_bf16(qf[1], k1, s[nt], 0, 0, 0);
        }

        if (t == qt) {                  // causal mask on diagonal tile
#pragma unroll
            for (int nt = 0; nt < 4; nt++) {
                int key = j0 + nt * 16 + l16;
#pragma unroll
                for (int r = 0; r < 4; r++) {
                    int q = qt * 64 + w * 16 + g * 4 + r;
                    if (key > q) s[nt][r] = -INFINITY;
                }
            }
        }

        // row max (reduce across 16 lanes of group; regs index q-rows)
        float tm[4];
#pragma unroll
        for (int r = 0; r < 4; r++)
            tm[r] = fmaxf(fmaxf(s[0][r], s[1][r]), fmaxf(s[2][r], s[3][r]));
#pragma unroll
        for (int x = 1; x <= 8; x <<= 1)
#pragma unroll
            for (int r = 0; r < 4; r++)
                tm[r] = fmaxf(tm[r], __shfl_xor(tm[r], x));

        float al[4];
#pragma unroll
        for (int r = 0; r < 4; r++) {
            float mn = fmaxf(mrun[r], tm[r]);
            al[r] = __expf(mrun[r] - mn);   // exp(-inf)=0 first tile
            mrun[r] = mn;
        }

        float rs[4] = {0.f, 0.f, 0.f, 0.f};
#pragma unroll
        for (int nt = 0; nt < 4; nt++)
#pragma unroll
            for (int r = 0; r < 4; r++) {
                float p = __expf(s[nt][r] - mrun[r]);  // masked -> 0
                rs[r] += p;
                Ps[w][(g * 4 + r) * AST + nt * 16 + l16] = f2b(p);
            }
#pragma unroll
        for (int x = 1; x <= 8; x <<= 1)
#pragma unroll
            for (int r = 0; r < 4; r++)
                rs[r] += __shfl_xor(rs[r], x);
#pragma unroll
        for (int r = 0; r < 4; r++)
            lrun[r] = lrun[r] * al[r] + rs[r];

#pragma unroll
        for (int nt = 0; nt < 4; nt++)
#pragma unroll
            for (int r = 0; r < 4; r++)
                o[nt][r] *= al[r];

        // O += P V  (A-frag of P from per-wave LDS; B-frag from Vt)
#pragma unroll
        for (int kf = 0; kf < 2; kf++) {
            bf16x8 pf = *(const bf16x8*)&Ps[w][l16 * AST + kf * 32 + g * 8];
#pragma unroll
            for (int nt = 0; nt < 4; nt++) {
                bf16x8 vf = *(const bf16x8*)&Vs[(nt * 16 + l16) * AST + kf * 32 + g * 8];
                o[nt] = __builtin_amdgcn_mfma_f32_16x16x32_bf16(pf, vf, o[nt], 0, 0, 0);
            }
        }
    }

    float inv[4];
#pragma unroll
    for (int r = 0; r < 4; r++) inv[r] = 1.f / lrun[r];
    int qg = qt * 64 + w * 16 + g * 4;
#pragma unroll
    for (int nt = 0; nt < 4; nt++)
#pragma unroll
        for (int r = 0; r < 4; r++)
            out[(size_t)(b * T_ + qg + r) * E_ + h * 64 + nt * 16 + l16] =
                f2b(o[nt][r] * inv[r]);
}

extern "C" void kernel_launch(void* const* d_in, const int* in_sizes, int n_in,
                              void* d_out, int out_size, void* d_ws, size_t ws_size,
                              hipStream_t stream) {
    const float* x    = (const float*)d_in[0];
    const float* Wq   = (const float*)d_in[1];
    const float* bq   = (const float*)d_in[2];
    const float* Wk   = (const float*)d_in[3];
    const float* bk   = (const float*)d_in[4];
    const float* Wv   = (const float*)d_in[5];
    const float* bv   = (const float*)d_in[6];
    const float* Wo   = (const float*)d_in[7];
    const float* bo   = (const float*)d_in[8];
    const float* W1   = (const float*)d_in[9];
    const float* b1   = (const float*)d_in[10];
    const float* W2   = (const float*)d_in[11];
    const float* b2   = (const float*)d_in[12];
    const float* ln1g = (const float*)d_in[13];
    const float* ln1b = (const float*)d_in[14];
    const float* ln2g = (const float*)d_in[15];
    const float* ln2b = (const float*)d_in[16];

    char* ws = (char*)d_ws;
    size_t off = 0;
    auto alloc = [&](size_t bytes) { char* p = ws + off; off += (bytes + 255) & ~(size_t)255; return p; };

    u16*   hB    = (u16*)  alloc((size_t)M_ * E_ * 2);        // LN1 out bf16
    u16*   WqkB  = (u16*)  alloc((size_t)2 * E_ * E_ * 2);    // packed q,k weights bf16
    u16*   WvB   = (u16*)  alloc((size_t)E_ * E_ * 2);
    u16*   WoB   = (u16*)  alloc((size_t)E_ * E_ * 2);
    u16*   W1B   = (u16*)  alloc((size_t)FF_ * E_ * 2);
    u16*   W2B   = (u16*)  alloc((size_t)E_ * FF_ * 2);
    float* bqk   = (float*)alloc(2 * E_ * 4);
    u16*   qkB   = (u16*)  alloc((size_t)M_ * 2 * E_ * 2);    // bf16 [M,2048], Q prescaled
    u16*   vtG   = (u16*)  alloc((size_t)M_ * E_ * 2);        // bf16 V transposed [B*1024, 2048]
    u16*   attnB = (u16*)  alloc((size_t)M_ * E_ * 2);        // attention out bf16
    float* x2    = (float*)alloc((size_t)M_ * E_ * 4);        // after out-proj + residual
    u16*   h2B   = (u16*)  alloc((size_t)M_ * E_ * 2);        // LN2 out bf16
    u16*   rB    = (u16*)  alloc((size_t)M_ * FF_ * 2);       // relu(ff1) bf16

    // weight conversions
    int nW = E_ * E_ / 4;
    cvt_bf16<<<(nW + 255) / 256, 256, 0, stream>>>(WqkB,           Wq, nW);
    cvt_bf16<<<(nW + 255) / 256, 256, 0, stream>>>(WqkB + E_ * E_, Wk, nW);
    cvt_bf16<<<(nW + 255) / 256, 256, 0, stream>>>(WvB, Wv, nW);
    cvt_bf16<<<(nW + 255) / 256, 256, 0, stream>>>(WoB, Wo, nW);
    int nW1 = FF_ * E_ / 4;
    cvt_bf16<<<(nW1 + 255) / 256, 256, 0, stream>>>(W1B, W1, nW1);
    cvt_bf16<<<(nW1 + 255) / 256, 256, 0, stream>>>(W2B, W2, nW1);
    copyf<<<4, 256, 0, stream>>>(bqk,      bq, E_);
    copyf<<<4, 256, 0, stream>>>(bqk + E_, bk, E_);

    // LN1
    ln_fwd<<<M_, 64, 0, stream>>>(hB, x, ln1g, ln1b);

    // Q|K projection -> bf16 [4096,2048], Q cols prescaled by 0.125
    gemm_bt<<<dim3(2 * E_ / 128, M_ / 128), 256, 0, stream>>>(
        hB, WqkB, bqk, nullptr, nullptr, qkB, M_, 2 * E_, E_, 0, 1, 0);

    // V projection -> bf16 transposed [B*1024, 2048]
    gemm_bt<<<dim3(E_ / 128, M_ / 128), 256, 0, stream>>>(
        hB, WvB, bv, nullptr, nullptr, vtG, M_, E_, E_, 0, 0, 1);

    // flash attention
    attn_mfma<<<B_ * H_ * (T_ / 64), 256, 0, stream>>>(qkB, vtG, attnB);

    // out projection + residual: x2 = x + attn @ Wo^T + bo
    gemm_bt<<<dim3(E_ / 128, M_ / 128), 256, 0, stream>>>(
        attnB, WoB, bo, x, x2, nullptr, M_, E_, E_, 0, 0, 0);

    // LN2
    ln_fwd<<<M_, 64, 0, stream>>>(h2B, x2, ln2g, ln2b);

    // FF1 + relu -> bf16
    gemm_bt<<<dim3(FF_ / 128, M_ / 128), 256, 0, stream>>>(
        h2B, W1B, b1, nullptr, nullptr, rB, M_, FF_, E_, 1, 0, 0);

    // FF2 + residual -> out
    gemm_bt<<<dim3(E_ / 128, M_ / 128), 256, 0, stream>>>(
        rB, W2B, b2, x2, (float*)d_out, nullptr, M_, E_, FF_, 0, 0, 0);
}

// Round 3
// 463.457 us; speedup vs baseline: 4.2065x; 1.2863x over previous
//
#include <hip/hip_runtime.h>

typedef unsigned short u16;
typedef __bf16 bf16x8 __attribute__((ext_vector_type(8)));
typedef float f32x4 __attribute__((ext_vector_type(4)));

#define E_ 1024
#define T_ 2048
#define B_ 2
#define H_ 16
#define FF_ 4096
#define M_ 4096   // B*T

__device__ __forceinline__ u16 f2b(float f) {
    union { float f; unsigned u; } c; c.f = f;
    unsigned r = c.u + 0x7FFFu + ((c.u >> 16) & 1u);
    return (u16)(r >> 16);
}

// async global->LDS, 16B per lane; LDS dest = wave-uniform base + lane*16
__device__ __forceinline__ void gl16(const u16* g, u16* l) {
    __builtin_amdgcn_global_load_lds(
        (__attribute__((address_space(1))) void*)g,
        (__attribute__((address_space(3))) void*)l, 16, 0, 0);
}

// ---------------- fused weight/bias conversion ----------------
// float4 index space: [0,786432) Wq|Wk|Wv -> WqkvB
//                     [786432,1048576) Wo -> WoB
//                     [1048576,2097152) W1 -> W1B
//                     [2097152,3145728) W2 -> W2B
//                     [3145728,3146496) bq|bk|bv -> bqkv (fp32)
__global__ void cvt_all(const float* __restrict__ Wq, const float* __restrict__ Wk,
                        const float* __restrict__ Wv, const float* __restrict__ Wo,
                        const float* __restrict__ W1, const float* __restrict__ W2,
                        const float* __restrict__ bq, const float* __restrict__ bk,
                        const float* __restrict__ bv,
                        u16* __restrict__ WqkvB, u16* __restrict__ WoB,
                        u16* __restrict__ W1B, u16* __restrict__ W2B,
                        float* __restrict__ bqkv) {
    int i = blockIdx.x * blockDim.x + threadIdx.x;
    if (i >= 3146496) return;
    if (i >= 3145728) {             // biases (fp32 copy)
        int j = i - 3145728;        // 0..767
        const float* s = (j < 256) ? bq : (j < 512) ? bk : bv;
        int jj = j & 255;
        *(float4*)&bqkv[j * 4] = *(const float4*)&s[jj * 4];
        return;
    }
    const float* src; u16* dst; int j;
    if (i < 786432) {
        src = (i < 262144) ? Wq : (i < 524288) ? Wk : Wv;
        j = i & 262143;
        dst = WqkvB + (i >> 18) * (E_ * E_);
    } else if (i < 1048576) { j = i - 786432;  src = Wo; dst = WoB; }
    else if (i < 2097152)   { j = i - 1048576; src = W1; dst = W1B; }
    else                    { j = i - 2097152; src = W2; dst = W2B; }
    float4 f = *(const float4*)&src[j * 4];
    ushort4 o;
    o.x = f2b(f.x); o.y = f2b(f.y); o.z = f2b(f.z); o.w = f2b(f.w);
    *(ushort4*)&dst[j * 4] = o;
}

// ---------------- LayerNorm: 1 wave per row of 1024 ----------------
__global__ __launch_bounds__(64) void ln_fwd(u16* __restrict__ out, const float* __restrict__ x,
                                             const float* __restrict__ g, const float* __restrict__ bta) {
    int row = blockIdx.x;
    int t = threadIdx.x;
    const float* xr = x + (size_t)row * E_;
    float v[16];
    float sum = 0.f, ss = 0.f;
#pragma unroll
    for (int c = 0; c < 4; c++) {
        float4 f = *(const float4*)&xr[c * 256 + t * 4];
        v[c * 4 + 0] = f.x; v[c * 4 + 1] = f.y; v[c * 4 + 2] = f.z; v[c * 4 + 3] = f.w;
        sum += f.x + f.y + f.z + f.w;
        ss += f.x * f.x + f.y * f.y + f.z * f.z + f.w * f.w;
    }
#pragma unroll
    for (int d = 32; d; d >>= 1) {
        sum += __shfl_xor(sum, d);
        ss  += __shfl_xor(ss, d);
    }
    float mu = sum * (1.f / E_);
    float var = ss * (1.f / E_) - mu * mu;
    float rs = rsqrtf(var + 1e-5f);
#pragma unroll
    for (int c = 0; c < 4; c++) {
        int idx = c * 256 + t * 4;
        float4 g4 = *(const float4*)&g[idx];
        float4 b4 = *(const float4*)&bta[idx];
        ushort4 o;
        o.x = f2b((v[c * 4 + 0] - mu) * rs * g4.x + b4.x);
        o.y = f2b((v[c * 4 + 1] - mu) * rs * g4.y + b4.y);
        o.z = f2b((v[c * 4 + 2] - mu) * rs * g4.z + b4.z);
        o.w = f2b((v[c * 4 + 3] - mu) * rs * g4.w + b4.w);
        *(ushort4*)&out[(size_t)row * E_ + idx] = o;
    }
}

// ---------------- bf16 MFMA GEMM (m97-style global_load_lds staging) ----------------
// C[M,N] = A[M,K] * Bt[N,K]^T. 128x128 tile, 256 thr (2x2 waves), BK=32.
// LDS unpadded [128][32] u16 (lane-contiguous for global_load_lds).
// qkvmode: N=3072. gn<1024: Q (*0.125 incl bias) -> outB[gm*2048+gn];
//          gn<2048: K -> outB[gm*2048+gn]; gn>=2048: V transposed -> outVt.
__global__ __launch_bounds__(256) void gemm_bt(
        const u16* __restrict__ A, const u16* __restrict__ Bt,
        const float* __restrict__ bias, const float* __restrict__ residual,
        float* __restrict__ outF, u16* __restrict__ outB, u16* __restrict__ outVt,
        int M, int N, int K, int relu, int qkvmode) {
    __shared__ __align__(16) u16 As[128 * 32];
    __shared__ __align__(16) u16 Bs[128 * 32];
    int tid = threadIdx.x;
    int m0 = blockIdx.y * 128, n0 = blockIdx.x * 128;
    int wave = tid >> 6, lane = tid & 63;
    int wm = wave & 1, wn = wave >> 1;
    int r16 = lane & 15, kg = lane >> 4;

    // staging: wave w covers rows [w*32, w*32+32) in two 16-row calls
    const u16* gA = A + (size_t)(m0 + wave * 32 + (lane >> 2)) * K + (lane & 3) * 8;
    const u16* gB = Bt + (size_t)(n0 + wave * 32 + (lane >> 2)) * K + (lane & 3) * 8;
    u16* lA = As + wave * 1024;   // (wave*32)*32
    u16* lB = Bs + wave * 1024;
    size_t row16 = (size_t)16 * K;

    f32x4 acc[4][4] = {};

    for (int k0 = 0; k0 < K; k0 += 32) {
        __syncthreads();
        gl16(gA + k0, lA);
        gl16(gA + k0 + row16, lA + 512);
        gl16(gB + k0, lB);
        gl16(gB + k0 + row16, lB + 512);
        __syncthreads();

        bf16x8 af[4], bfr[4];
#pragma unroll
        for (int mt = 0; mt < 4; mt++)
            af[mt] = *(const bf16x8*)&As[(wm * 64 + mt * 16 + r16) * 32 + kg * 8];
#pragma unroll
        for (int nt = 0; nt < 4; nt++)
            bfr[nt] = *(const bf16x8*)&Bs[(wn * 64 + nt * 16 + r16) * 32 + kg * 8];
#pragma unroll
        for (int mt = 0; mt < 4; mt++)
#pragma unroll
            for (int nt = 0; nt < 4; nt++)
                acc[mt][nt] = __builtin_amdgcn_mfma_f32_16x16x32_bf16(af[mt], bfr[nt], acc[mt][nt], 0, 0, 0);
    }

#pragma unroll
    for (int mt = 0; mt < 4; mt++) {
#pragma unroll
        for (int nt = 0; nt < 4; nt++) {
            int gm = m0 + wm * 64 + mt * 16 + kg * 4;
            int gn = n0 + wn * 64 + nt * 16 + r16;
            float bv = bias[gn];
            if (qkvmode) {
                if (gn < 2048) {
                    float scl = (gn < 1024) ? 0.125f : 1.0f;
#pragma unroll
                    for (int r = 0; r < 4; r++)
                        outB[(size_t)(gm + r) * 2048 + gn] = f2b((acc[mt][nt][r] + bv) * scl);
                } else {
                    int bq_ = gm >> 11, tq = gm & 2047, d = gn - 2048;
                    ushort4 ov;
                    ov.x = f2b(acc[mt][nt][0] + bv);
                    ov.y = f2b(acc[mt][nt][1] + bv);
                    ov.z = f2b(acc[mt][nt][2] + bv);
                    ov.w = f2b(acc[mt][nt][3] + bv);
                    *(ushort4*)&outVt[((size_t)(bq_ * 1024 + d)) * 2048 + tq] = ov;
                }
            } else {
#pragma unroll
                for (int r = 0; r < 4; r++) {
                    float v = acc[mt][nt][r] + bv;
                    size_t off = (size_t)(gm + r) * N + gn;
                    if (residual) v += residual[off];
                    if (relu) v = fmaxf(v, 0.f);
                    if (outF) outF[off] = v;
                    else outB[off] = f2b(v);
                }
            }
        }
    }
}

// ---------------- MFMA flash attention (bf16, causal) ----------------
// grid = 1024; bz = qt*32 + b*16 + h  (qt in HIGH bits -> same-CU blocks get mixed qt).
// qk: [M,2048] bf16 (Q prescaled by 0.125 | K);  vt: [B*1024, 2048] bf16 V^T.
// Register-prefetch of next K/V tile issued AFTER the consume-barrier so the
// loads overlap the whole compute phase (not drained by the staging barrier).
#define AST 72   // 144B row stride: 36 dwords === 4 mod 32 -> conflict-free b128
__global__ __launch_bounds__(256) void attn_mfma(
        const u16* __restrict__ qk, const u16* __restrict__ vt,
        u16* __restrict__ out) {
    __shared__ __align__(16) u16 Ks[64 * AST];     // K[key][d]
    __shared__ __align__(16) u16 Vs[64 * AST];     // Vt[d][key]
    __shared__ __align__(16) u16 Ps[4][16 * AST];  // per-wave P[q][key]

    int bz = blockIdx.x;
    int h  = bz & 15;
    int b  = (bz >> 4) & 1;
    int qt = bz >> 5;

    int tid = threadIdx.x;
    int w = tid >> 6, lane = tid & 63;
    int g = lane >> 4, l16 = lane & 15;

    // Q fragments (A-layout: m=l16, k=g*8+j), Q already prescaled
    int qrow = qt * 64 + w * 16 + l16;
    bf16x8 qf[2];
    qf[0] = *(const bf16x8*)&qk[(size_t)(b * T_ + qrow) * 2048 + h * 64 + g * 8];
    qf[1] = *(const bf16x8*)&qk[(size_t)(b * T_ + qrow) * 2048 + h * 64 + 32 + g * 8];

    f32x4 o[4] = {};
    float mrun[4] = {-INFINITY, -INFINITY, -INFINITY, -INFINITY};
    float lrun[4] = {0.f, 0.f, 0.f, 0.f};

    // staging coords: thread stages rows c>>3, 8 u16 chunk (c&7)*8, c in {tid, tid+256}
    int r1 = tid >> 3, col1 = (tid & 7) * 8;
    int r2 = (tid + 256) >> 3, col2 = ((tid + 256) & 7) * 8;
    const u16* gK = qk + (size_t)(b * T_) * 2048 + 1024 + h * 64;
    const u16* gV = vt + (size_t)(b * 1024 + h * 64) * 2048;

    uint4 kr1, kr2, vr1, vr2;
    {
        kr1 = *(const uint4*)&gK[(size_t)r1 * 2048 + col1];
        kr2 = *(const uint4*)&gK[(size_t)r2 * 2048 + col2];
        vr1 = *(const uint4*)&gV[(size_t)r1 * 2048 + col1];
        vr2 = *(const uint4*)&gV[(size_t)r2 * 2048 + col2];
    }

    for (int t = 0; t <= qt; t++) {
        int j0 = t * 64;
        __syncthreads();                      // (A) prev tile fully consumed
        *(uint4*)&Ks[r1 * AST + col1] = kr1;
        *(uint4*)&Ks[r2 * AST + col2] = kr2;
        *(uint4*)&Vs[r1 * AST + col1] = vr1;
        *(uint4*)&Vs[r2 * AST + col2] = vr2;
        __syncthreads();                      // (B) LDS valid
        if (t < qt) {                         // prefetch next tile AFTER (B)
            int j1 = j0 + 64;
            kr1 = *(const uint4*)&gK[(size_t)(j1 + r1) * 2048 + col1];
            kr2 = *(const uint4*)&gK[(size_t)(j1 + r2) * 2048 + col2];
            vr1 = *(const uint4*)&gV[(size_t)r1 * 2048 + j1 + col1];
            vr2 = *(const uint4*)&gV[(size_t)r2 * 2048 + j1 + col2];
        }

        // S = Q K^T  (C-layout: key = nt*16+l16, q = g*4+r)
        f32x4 s[4] = {};
#pragma unroll
        for (int nt = 0; nt < 4; nt++) {
            bf16x8 k0 = *(const bf16x8*)&Ks[(nt * 16 + l16) * AST + g * 8];
            bf16x8 k1 = *(const bf16x8*)&Ks[(nt * 16 + l16) * AST + 32 + g * 8];
            s[nt] = __builtin_amdgcn_mfma_f32_16x16x32_bf16(qf[0], k0, s[nt], 0, 0, 0);
            s[nt] = __builtin_amdgcn_mfma_f32_16x16x32_bf16(qf[1], k1, s[nt], 0, 0, 0);
        }

        if (t == qt) {                        // causal mask on diagonal tile
#pragma unroll
            for (int nt = 0; nt < 4; nt++) {
                int key = j0 + nt * 16 + l16;
#pragma unroll
                for (int r = 0; r < 4; r++) {
                    int q = qt * 64 + w * 16 + g * 4 + r;
                    if (key > q) s[nt][r] = -INFINITY;
                }
            }
        }

        float tm[4];
#pragma unroll
        for (int r = 0; r < 4; r++)
            tm[r] = fmaxf(fmaxf(s[0][r], s[1][r]), fmaxf(s[2][r], s[3][r]));
#pragma unroll
        for (int x = 1; x <= 8; x <<= 1)
#pragma unroll
            for (int r = 0; r < 4; r++)
                tm[r] = fmaxf(tm[r], __shfl_xor(tm[r], x));

        float al[4];
#pragma unroll
        for (int r = 0; r < 4; r++) {
            float mn = fmaxf(mrun[r], tm[r]);
            al[r] = __expf(mrun[r] - mn);
            mrun[r] = mn;
        }

        float rs[4] = {0.f, 0.f, 0.f, 0.f};
#pragma unroll
        for (int nt = 0; nt < 4; nt++)
#pragma unroll
            for (int r = 0; r < 4; r++) {
                float p = __expf(s[nt][r] - mrun[r]);
                rs[r] += p;
                Ps[w][(g * 4 + r) * AST + nt * 16 + l16] = f2b(p);
            }
#pragma unroll
        for (int x = 1; x <= 8; x <<= 1)
#pragma unroll
            for (int r = 0; r < 4; r++)
                rs[r] += __shfl_xor(rs[r], x);
#pragma unroll
        for (int r = 0; r < 4; r++)
            lrun[r] = lrun[r] * al[r] + rs[r];

#pragma unroll
        for (int nt = 0; nt < 4; nt++)
#pragma unroll
            for (int r = 0; r < 4; r++)
                o[nt][r] *= al[r];

        // O += P V
#pragma unroll
        for (int kf = 0; kf < 2; kf++) {
            bf16x8 pf = *(const bf16x8*)&Ps[w][l16 * AST + kf * 32 + g * 8];
#pragma unroll
            for (int nt = 0; nt < 4; nt++) {
                bf16x8 vf = *(const bf16x8*)&Vs[(nt * 16 + l16) * AST + kf * 32 + g * 8];
                o[nt] = __builtin_amdgcn_mfma_f32_16x16x32_bf16(pf, vf, o[nt], 0, 0, 0);
            }
        }
    }

    float inv[4];
#pragma unroll
    for (int r = 0; r < 4; r++) inv[r] = 1.f / lrun[r];
    int qg = qt * 64 + w * 16 + g * 4;
#pragma unroll
    for (int nt = 0; nt < 4; nt++)
#pragma unroll
        for (int r = 0; r < 4; r++)
            out[(size_t)(b * T_ + qg + r) * E_ + h * 64 + nt * 16 + l16] =
                f2b(o[nt][r] * inv[r]);
}

extern "C" void kernel_launch(void* const* d_in, const int* in_sizes, int n_in,
                              void* d_out, int out_size, void* d_ws, size_t ws_size,
                              hipStream_t stream) {
    const float* x    = (const float*)d_in[0];
    const float* Wq   = (const float*)d_in[1];
    const float* bq   = (const float*)d_in[2];
    const float* Wk   = (const float*)d_in[3];
    const float* bk   = (const float*)d_in[4];
    const float* Wv   = (const float*)d_in[5];
    const float* bv   = (const float*)d_in[6];
    const float* Wo   = (const float*)d_in[7];
    const float* bo   = (const float*)d_in[8];
    const float* W1   = (const float*)d_in[9];
    const float* b1   = (const float*)d_in[10];
    const float* W2   = (const float*)d_in[11];
    const float* b2   = (const float*)d_in[12];
    const float* ln1g = (const float*)d_in[13];
    const float* ln1b = (const float*)d_in[14];
    const float* ln2g = (const float*)d_in[15];
    const float* ln2b = (const float*)d_in[16];

    char* ws = (char*)d_ws;
    size_t off = 0;
    auto alloc = [&](size_t bytes) { char* p = ws + off; off += (bytes + 255) & ~(size_t)255; return p; };

    u16*   hB    = (u16*)  alloc((size_t)M_ * E_ * 2);        // LN1 out bf16
    u16*   WqkvB = (u16*)  alloc((size_t)3 * E_ * E_ * 2);    // packed q,k,v weights bf16
    u16*   WoB   = (u16*)  alloc((size_t)E_ * E_ * 2);
    u16*   W1B   = (u16*)  alloc((size_t)FF_ * E_ * 2);
    u16*   W2B   = (u16*)  alloc((size_t)E_ * FF_ * 2);
    float* bqkv  = (float*)alloc(3 * E_ * 4);
    u16*   qkB   = (u16*)  alloc((size_t)M_ * 2 * E_ * 2);    // bf16 [M,2048], Q prescaled
    u16*   vtG   = (u16*)  alloc((size_t)M_ * E_ * 2);        // bf16 V^T [B*1024, 2048]
    u16*   attnB = (u16*)  alloc((size_t)M_ * E_ * 2);        // attention out bf16
    float* x2    = (float*)alloc((size_t)M_ * E_ * 4);        // after out-proj + residual
    u16*   h2B   = (u16*)  alloc((size_t)M_ * E_ * 2);        // LN2 out bf16
    u16*   rB    = (u16*)  alloc((size_t)M_ * FF_ * 2);       // relu(ff1) bf16

    // fused weight/bias conversion (one launch)
    cvt_all<<<12291, 256, 0, stream>>>(Wq, Wk, Wv, Wo, W1, W2, bq, bk, bv,
                                       WqkvB, WoB, W1B, W2B, bqkv);

    // LN1
    ln_fwd<<<M_, 64, 0, stream>>>(hB, x, ln1g, ln1b);

    // fused QKV projection: [4096,1024] x [3072,1024]^T
    gemm_bt<<<dim3(3 * E_ / 128, M_ / 128), 256, 0, stream>>>(
        hB, WqkvB, bqkv, nullptr, nullptr, qkB, vtG, M_, 3 * E_, E_, 0, 1);

    // flash attention
    attn_mfma<<<B_ * H_ * (T_ / 64), 256, 0, stream>>>(qkB, vtG, attnB);

    // out projection + residual: x2 = x + attn @ Wo^T + bo
    gemm_bt<<<dim3(E_ / 128, M_ / 128), 256, 0, stream>>>(
        attnB, WoB, bo, x, x2, nullptr, nullptr, M_, E_, E_, 0, 0);

    // LN2
    ln_fwd<<<M_, 64, 0, stream>>>(h2B, x2, ln2g, ln2b);

    // FF1 + relu -> bf16
    gemm_bt<<<dim3(FF_ / 128, M_ / 128), 256, 0, stream>>>(
        h2B, W1B, b1, nullptr, nullptr, rB, nullptr, M_, FF_, E_, 1, 0);

    // FF2 + residual -> out
    gemm_bt<<<dim3(E_ / 128, M_ / 128), 256, 0, stream>>>(
        rB, W2B, b2, x2, (float*)d_out, nullptr, nullptr, M_, E_, FF_, 0, 0);
}

// Round 4
// 448.176 us; speedup vs baseline: 4.3500x; 1.0341x over previous
//
#include <hip/hip_runtime.h>

typedef unsigned short u16;
typedef __bf16 bf16x8 __attribute__((ext_vector_type(8)));
typedef float f32x4 __attribute__((ext_vector_type(4)));

#define E_ 1024
#define T_ 2048
#define B_ 2
#define H_ 16
#define FF_ 4096
#define M_ 4096   // B*T

__device__ __forceinline__ u16 f2b(float f) {
    union { float f; unsigned u; } c; c.f = f;
    unsigned r = c.u + 0x7FFFu + ((c.u >> 16) & 1u);
    return (u16)(r >> 16);
}

// async global->LDS, 16B per lane; LDS dest = wave-uniform base + lane*16
__device__ __forceinline__ void gl16(const u16* g, u16* l) {
    __builtin_amdgcn_global_load_lds(
        (__attribute__((address_space(1))) void*)g,
        (__attribute__((address_space(3))) void*)l, 16, 0, 0);
}

// ---------------- fused weight/bias conversion ----------------
__global__ void cvt_all(const float* __restrict__ Wq, const float* __restrict__ Wk,
                        const float* __restrict__ Wv, const float* __restrict__ Wo,
                        const float* __restrict__ W1, const float* __restrict__ W2,
                        const float* __restrict__ bq, const float* __restrict__ bk,
                        const float* __restrict__ bv,
                        u16* __restrict__ WqkvB, u16* __restrict__ WoB,
                        u16* __restrict__ W1B, u16* __restrict__ W2B,
                        float* __restrict__ bqkv) {
    int i = blockIdx.x * blockDim.x + threadIdx.x;
    if (i >= 3146496) return;
    if (i >= 3145728) {             // biases (fp32 copy)
        int j = i - 3145728;        // 0..767
        const float* s = (j < 256) ? bq : (j < 512) ? bk : bv;
        int jj = j & 255;
        *(float4*)&bqkv[j * 4] = *(const float4*)&s[jj * 4];
        return;
    }
    const float* src; u16* dst; int j;
    if (i < 786432) {
        src = (i < 262144) ? Wq : (i < 524288) ? Wk : Wv;
        j = i & 262143;
        dst = WqkvB + (i >> 18) * (E_ * E_);
    } else if (i < 1048576) { j = i - 786432;  src = Wo; dst = WoB; }
    else if (i < 2097152)   { j = i - 1048576; src = W1; dst = W1B; }
    else                    { j = i - 2097152; src = W2; dst = W2B; }
    float4 f = *(const float4*)&src[j * 4];
    ushort4 o;
    o.x = f2b(f.x); o.y = f2b(f.y); o.z = f2b(f.z); o.w = f2b(f.w);
    *(ushort4*)&dst[j * 4] = o;
}

// ---------------- LayerNorm: 1 wave per row of 1024 ----------------
__global__ __launch_bounds__(64) void ln_fwd(u16* __restrict__ out, const float* __restrict__ x,
                                             const float* __restrict__ g, const float* __restrict__ bta) {
    int row = blockIdx.x;
    int t = threadIdx.x;
    const float* xr = x + (size_t)row * E_;
    float v[16];
    float sum = 0.f, ss = 0.f;
#pragma unroll
    for (int c = 0; c < 4; c++) {
        float4 f = *(const float4*)&xr[c * 256 + t * 4];
        v[c * 4 + 0] = f.x; v[c * 4 + 1] = f.y; v[c * 4 + 2] = f.z; v[c * 4 + 3] = f.w;
        sum += f.x + f.y + f.z + f.w;
        ss += f.x * f.x + f.y * f.y + f.z * f.z + f.w * f.w;
    }
#pragma unroll
    for (int d = 32; d; d >>= 1) {
        sum += __shfl_xor(sum, d);
        ss  += __shfl_xor(ss, d);
    }
    float mu = sum * (1.f / E_);
    float var = ss * (1.f / E_) - mu * mu;
    float rs = rsqrtf(var + 1e-5f);
#pragma unroll
    for (int c = 0; c < 4; c++) {
        int idx = c * 256 + t * 4;
        float4 g4 = *(const float4*)&g[idx];
        float4 b4 = *(const float4*)&bta[idx];
        ushort4 o;
        o.x = f2b((v[c * 4 + 0] - mu) * rs * g4.x + b4.x);
        o.y = f2b((v[c * 4 + 1] - mu) * rs * g4.y + b4.y);
        o.z = f2b((v[c * 4 + 2] - mu) * rs * g4.z + b4.z);
        o.w = f2b((v[c * 4 + 3] - mu) * rs * g4.w + b4.w);
        *(ushort4*)&out[(size_t)row * E_ + idx] = o;
    }
}

// ---------------- bf16 MFMA GEMM, double-buffered global_load_lds pipeline ----------------
// C[M,N] = A[M,K] * Bt[N,K]^T. 128x128 tile, 256 thr (2x2 waves), BK=32.
// One barrier per k-step; prefetch for step k+1 issued right after the barrier
// so it is in flight during the whole compute phase (drained by the NEXT
// barrier's implicit vmcnt(0)). Critical at 1 block/CU (FF2/out-proj grids).
__global__ __launch_bounds__(256) void gemm_bt(
        const u16* __restrict__ A, const u16* __restrict__ Bt,
        const float* __restrict__ bias, const float* __restrict__ residual,
        float* __restrict__ outF, u16* __restrict__ outB, u16* __restrict__ outVt,
        int M, int N, int K, int relu, int qkvmode) {
    __shared__ __align__(16) u16 As[2][128 * 32];
    __shared__ __align__(16) u16 Bs[2][128 * 32];
    int tid = threadIdx.x;
    int m0 = blockIdx.y * 128, n0 = blockIdx.x * 128;
    int wave = tid >> 6, lane = tid & 63;
    int wm = wave & 1, wn = wave >> 1;
    int r16 = lane & 15, kg = lane >> 4;

    // staging: wave w covers rows [w*32, w*32+32) in two 16-row calls;
    // per-lane LDS offset within a call is lane*16B (gl16 requirement).
    const u16* gA = A + (size_t)(m0 + wave * 32 + (lane >> 2)) * K + (lane & 3) * 8;
    const u16* gB = Bt + (size_t)(n0 + wave * 32 + (lane >> 2)) * K + (lane & 3) * 8;
    size_t row16 = (size_t)16 * K;
    int woff = wave * 1024;        // (wave*32 rows) * 32 elems

    f32x4 acc[4][4] = {};

    const int nk = K >> 5;
    // prologue: prefetch k-step 0 into buffer 0
    gl16(gA, As[0] + woff);
    gl16(gA + row16, As[0] + woff + 512);
    gl16(gB, Bs[0] + woff);
    gl16(gB + row16, Bs[0] + woff + 512);

    for (int ks = 0; ks < nk; ks++) {
        int cur = ks & 1;
        __syncthreads();                 // drains own gl16s (vmcnt0) + barrier
        if (ks + 1 < nk) {               // prefetch next step into other buffer
            int k1 = (ks + 1) << 5;
            int nxt = cur ^ 1;
            gl16(gA + k1, As[nxt] + woff);
            gl16(gA + k1 + row16, As[nxt] + woff + 512);
            gl16(gB + k1, Bs[nxt] + woff);
            gl16(gB + k1 + row16, Bs[nxt] + woff + 512);
        }

        bf16x8 af[4], bfr[4];
#pragma unroll
        for (int mt = 0; mt < 4; mt++)
            af[mt] = *(const bf16x8*)&As[cur][(wm * 64 + mt * 16 + r16) * 32 + kg * 8];
#pragma unroll
        for (int nt = 0; nt < 4; nt++)
            bfr[nt] = *(const bf16x8*)&Bs[cur][(wn * 64 + nt * 16 + r16) * 32 + kg * 8];
#pragma unroll
        for (int mt = 0; mt < 4; mt++)
#pragma unroll
            for (int nt = 0; nt < 4; nt++)
                acc[mt][nt] = __builtin_amdgcn_mfma_f32_16x16x32_bf16(af[mt], bfr[nt], acc[mt][nt], 0, 0, 0);
    }

#pragma unroll
    for (int mt = 0; mt < 4; mt++) {
#pragma unroll
        for (int nt = 0; nt < 4; nt++) {
            int gm = m0 + wm * 64 + mt * 16 + kg * 4;
            int gn = n0 + wn * 64 + nt * 16 + r16;
            float bv = bias[gn];
            if (qkvmode) {
                if (gn < 2048) {
                    float scl = (gn < 1024) ? 0.125f : 1.0f;
#pragma unroll
                    for (int r = 0; r < 4; r++)
                        outB[(size_t)(gm + r) * 2048 + gn] = f2b((acc[mt][nt][r] + bv) * scl);
                } else {
                    int bq_ = gm >> 11, tq = gm & 2047, d = gn - 2048;
                    ushort4 ov;
                    ov.x = f2b(acc[mt][nt][0] + bv);
                    ov.y = f2b(acc[mt][nt][1] + bv);
                    ov.z = f2b(acc[mt][nt][2] + bv);
                    ov.w = f2b(acc[mt][nt][3] + bv);
                    *(ushort4*)&outVt[((size_t)(bq_ * 1024 + d)) * 2048 + tq] = ov;
                }
            } else {
#pragma unroll
                for (int r = 0; r < 4; r++) {
                    float v = acc[mt][nt][r] + bv;
                    size_t off = (size_t)(gm + r) * N + gn;
                    if (residual) v += residual[off];
                    if (relu) v = fmaxf(v, 0.f);
                    if (outF) outF[off] = v;
                    else outB[off] = f2b(v);
                }
            }
        }
    }
}

// ---------------- MFMA flash attention (bf16, causal) ----------------
// grid = 1024; bz = qt*32 + b*16 + h  (qt in HIGH bits -> same-CU blocks get mixed qt).
#define AST 72   // 144B row stride: 36 dwords === 4 mod 32 -> conflict-free b128
__global__ __launch_bounds__(256) void attn_mfma(
        const u16* __restrict__ qk, const u16* __restrict__ vt,
        u16* __restrict__ out) {
    __shared__ __align__(16) u16 Ks[64 * AST];     // K[key][d]
    __shared__ __align__(16) u16 Vs[64 * AST];     // Vt[d][key]
    __shared__ __align__(16) u16 Ps[4][16 * AST];  // per-wave P[q][key]

    int bz = blockIdx.x;
    int h  = bz & 15;
    int b  = (bz >> 4) & 1;
    int qt = bz >> 5;

    int tid = threadIdx.x;
    int w = tid >> 6, lane = tid & 63;
    int g = lane >> 4, l16 = lane & 15;

    int qrow = qt * 64 + w * 16 + l16;
    bf16x8 qf[2];
    qf[0] = *(const bf16x8*)&qk[(size_t)(b * T_ + qrow) * 2048 + h * 64 + g * 8];
    qf[1] = *(const bf16x8*)&qk[(size_t)(b * T_ + qrow) * 2048 + h * 64 + 32 + g * 8];

    f32x4 o[4] = {};
    float mrun[4] = {-INFINITY, -INFINITY, -INFINITY, -INFINITY};
    float lrun[4] = {0.f, 0.f, 0.f, 0.f};

    int r1 = tid >> 3, col1 = (tid & 7) * 8;
    int r2 = (tid + 256) >> 3, col2 = ((tid + 256) & 7) * 8;
    const u16* gK = qk + (size_t)(b * T_) * 2048 + 1024 + h * 64;
    const u16* gV = vt + (size_t)(b * 1024 + h * 64) * 2048;

    uint4 kr1, kr2, vr1, vr2;
    {
        kr1 = *(const uint4*)&gK[(size_t)r1 * 2048 + col1];
        kr2 = *(const uint4*)&gK[(size_t)r2 * 2048 + col2];
        vr1 = *(const uint4*)&gV[(size_t)r1 * 2048 + col1];
        vr2 = *(const uint4*)&gV[(size_t)r2 * 2048 + col2];
    }

    for (int t = 0; t <= qt; t++) {
        int j0 = t * 64;
        __syncthreads();                      // (A) prev tile fully consumed
        *(uint4*)&Ks[r1 * AST + col1] = kr1;
        *(uint4*)&Ks[r2 * AST + col2] = kr2;
        *(uint4*)&Vs[r1 * AST + col1] = vr1;
        *(uint4*)&Vs[r2 * AST + col2] = vr2;
        __syncthreads();                      // (B) LDS valid
        if (t < qt) {                         // prefetch next tile AFTER (B)
            int j1 = j0 + 64;
            kr1 = *(const uint4*)&gK[(size_t)(j1 + r1) * 2048 + col1];
            kr2 = *(const uint4*)&gK[(size_t)(j1 + r2) * 2048 + col2];
            vr1 = *(const uint4*)&gV[(size_t)r1 * 2048 + j1 + col1];
            vr2 = *(const uint4*)&gV[(size_t)r2 * 2048 + j1 + col2];
        }

        f32x4 s[4] = {};
#pragma unroll
        for (int nt = 0; nt < 4; nt++) {
            bf16x8 k0 = *(const bf16x8*)&Ks[(nt * 16 + l16) * AST + g * 8];
            bf16x8 k1 = *(const bf16x8*)&Ks[(nt * 16 + l16) * AST + 32 + g * 8];
            s[nt] = __builtin_amdgcn_mfma_f32_16x16x32_bf16(qf[0], k0, s[nt], 0, 0, 0);
            s[nt] = __builtin_amdgcn_mfma_f32_16x16x32_bf16(qf[1], k1, s[nt], 0, 0, 0);
        }

        if (t == qt) {
#pragma unroll
            for (int nt = 0; nt < 4; nt++) {
                int key = j0 + nt * 16 + l16;
#pragma unroll
                for (int r = 0; r < 4; r++) {
                    int q = qt * 64 + w * 16 + g * 4 + r;
                    if (key > q) s[nt][r] = -INFINITY;
                }
            }
        }

        float tm[4];
#pragma unroll
        for (int r = 0; r < 4; r++)
            tm[r] = fmaxf(fmaxf(s[0][r], s[1][r]), fmaxf(s[2][r], s[3][r]));
#pragma unroll
        for (int x = 1; x <= 8; x <<= 1)
#pragma unroll
            for (int r = 0; r < 4; r++)
                tm[r] = fmaxf(tm[r], __shfl_xor(tm[r], x));

        float al[4];
#pragma unroll
        for (int r = 0; r < 4; r++) {
            float mn = fmaxf(mrun[r], tm[r]);
            al[r] = __expf(mrun[r] - mn);
            mrun[r] = mn;
        }

        float rs[4] = {0.f, 0.f, 0.f, 0.f};
#pragma unroll
        for (int nt = 0; nt < 4; nt++)
#pragma unroll
            for (int r = 0; r < 4; r++) {
                float p = __expf(s[nt][r] - mrun[r]);
                rs[r] += p;
                Ps[w][(g * 4 + r) * AST + nt * 16 + l16] = f2b(p);
            }
#pragma unroll
        for (int x = 1; x <= 8; x <<= 1)
#pragma unroll
            for (int r = 0; r < 4; r++)
                rs[r] += __shfl_xor(rs[r], x);
#pragma unroll
        for (int r = 0; r < 4; r++)
            lrun[r] = lrun[r] * al[r] + rs[r];

#pragma unroll
        for (int nt = 0; nt < 4; nt++)
#pragma unroll
            for (int r = 0; r < 4; r++)
                o[nt][r] *= al[r];

#pragma unroll
        for (int kf = 0; kf < 2; kf++) {
            bf16x8 pf = *(const bf16x8*)&Ps[w][l16 * AST + kf * 32 + g * 8];
#pragma unroll
            for (int nt = 0; nt < 4; nt++) {
                bf16x8 vf = *(const bf16x8*)&Vs[(nt * 16 + l16) * AST + kf * 32 + g * 8];
                o[nt] = __builtin_amdgcn_mfma_f32_16x16x32_bf16(pf, vf, o[nt], 0, 0, 0);
            }
        }
    }

    float inv[4];
#pragma unroll
    for (int r = 0; r < 4; r++) inv[r] = 1.f / lrun[r];
    int qg = qt * 64 + w * 16 + g * 4;
#pragma unroll
    for (int nt = 0; nt < 4; nt++)
#pragma unroll
        for (int r = 0; r < 4; r++)
            out[(size_t)(b * T_ + qg + r) * E_ + h * 64 + nt * 16 + l16] =
                f2b(o[nt][r] * inv[r]);
}

extern "C" void kernel_launch(void* const* d_in, const int* in_sizes, int n_in,
                              void* d_out, int out_size, void* d_ws, size_t ws_size,
                              hipStream_t stream) {
    const float* x    = (const float*)d_in[0];
    const float* Wq   = (const float*)d_in[1];
    const float* bq   = (const float*)d_in[2];
    const float* Wk   = (const float*)d_in[3];
    const float* bk   = (const float*)d_in[4];
    const float* Wv   = (const float*)d_in[5];
    const float* bv   = (const float*)d_in[6];
    const float* Wo   = (const float*)d_in[7];
    const float* bo   = (const float*)d_in[8];
    const float* W1   = (const float*)d_in[9];
    const float* b1   = (const float*)d_in[10];
    const float* W2   = (const float*)d_in[11];
    const float* b2   = (const float*)d_in[12];
    const float* ln1g = (const float*)d_in[13];
    const float* ln1b = (const float*)d_in[14];
    const float* ln2g = (const float*)d_in[15];
    const float* ln2b = (const float*)d_in[16];

    char* ws = (char*)d_ws;
    size_t off = 0;
    auto alloc = [&](size_t bytes) { char* p = ws + off; off += (bytes + 255) & ~(size_t)255; return p; };

    u16*   hB    = (u16*)  alloc((size_t)M_ * E_ * 2);        // LN1 out bf16
    u16*   WqkvB = (u16*)  alloc((size_t)3 * E_ * E_ * 2);    // packed q,k,v weights bf16
    u16*   WoB   = (u16*)  alloc((size_t)E_ * E_ * 2);
    u16*   W1B   = (u16*)  alloc((size_t)FF_ * E_ * 2);
    u16*   W2B   = (u16*)  alloc((size_t)E_ * FF_ * 2);
    float* bqkv  = (float*)alloc(3 * E_ * 4);
    u16*   qkB   = (u16*)  alloc((size_t)M_ * 2 * E_ * 2);    // bf16 [M,2048], Q prescaled
    u16*   vtG   = (u16*)  alloc((size_t)M_ * E_ * 2);        // bf16 V^T [B*1024, 2048]
    u16*   attnB = (u16*)  alloc((size_t)M_ * E_ * 2);        // attention out bf16
    float* x2    = (float*)alloc((size_t)M_ * E_ * 4);        // after out-proj + residual
    u16*   h2B   = (u16*)  alloc((size_t)M_ * E_ * 2);        // LN2 out bf16
    u16*   rB    = (u16*)  alloc((size_t)M_ * FF_ * 2);       // relu(ff1) bf16

    // fused weight/bias conversion (one launch)
    cvt_all<<<12291, 256, 0, stream>>>(Wq, Wk, Wv, Wo, W1, W2, bq, bk, bv,
                                       WqkvB, WoB, W1B, W2B, bqkv);

    // LN1
    ln_fwd<<<M_, 64, 0, stream>>>(hB, x, ln1g, ln1b);

    // fused QKV projection: [4096,1024] x [3072,1024]^T
    gemm_bt<<<dim3(3 * E_ / 128, M_ / 128), 256, 0, stream>>>(
        hB, WqkvB, bqkv, nullptr, nullptr, qkB, vtG, M_, 3 * E_, E_, 0, 1);

    // flash attention
    attn_mfma<<<B_ * H_ * (T_ / 64), 256, 0, stream>>>(qkB, vtG, attnB);

    // out projection + residual: x2 = x + attn @ Wo^T + bo
    gemm_bt<<<dim3(E_ / 128, M_ / 128), 256, 0, stream>>>(
        attnB, WoB, bo, x, x2, nullptr, nullptr, M_, E_, E_, 0, 0);

    // LN2
    ln_fwd<<<M_, 64, 0, stream>>>(h2B, x2, ln2g, ln2b);

    // FF1 + relu -> bf16
    gemm_bt<<<dim3(FF_ / 128, M_ / 128), 256, 0, stream>>>(
        h2B, W1B, b1, nullptr, nullptr, rB, nullptr, M_, FF_, E_, 1, 0);

    // FF2 + residual -> out
    gemm_bt<<<dim3(E_ / 128, M_ / 128), 256, 0, stream>>>(
        rB, W2B, b2, x2, (float*)d_out, nullptr, nullptr, M_, E_, FF_, 0, 0);
}

// Round 5
// 411.953 us; speedup vs baseline: 4.7325x; 1.0879x over previous
//
#include <hip/hip_runtime.h>

typedef unsigned short u16;
typedef __bf16 bf16x8 __attribute__((ext_vector_type(8)));
typedef float f32x4 __attribute__((ext_vector_type(4)));

#define E_ 1024
#define T_ 2048
#define B_ 2
#define H_ 16
#define FF_ 4096
#define M_ 4096   // B*T

__device__ __forceinline__ u16 f2b(float f) {
    union { float f; unsigned u; } c; c.f = f;
    unsigned r = c.u + 0x7FFFu + ((c.u >> 16) & 1u);
    return (u16)(r >> 16);
}

// async global->LDS, 16B per lane; LDS dest = wave-uniform base + lane*16
__device__ __forceinline__ void gl16(const u16* g, u16* l) {
    __builtin_amdgcn_global_load_lds(
        (__attribute__((address_space(1))) void*)g,
        (__attribute__((address_space(3))) void*)l, 16, 0, 0);
}

// ---------------- fused weight/bias conversion + LN1 ----------------
// blocks [0,1024): LN1 (4 rows per block, 1 wave per row)
// blocks [1024, 1024+12291): weight cvt in float4 index space (see R2 notes)
__global__ __launch_bounds__(256) void cvt_ln(
        const float* __restrict__ Wq, const float* __restrict__ Wk,
        const float* __restrict__ Wv, const float* __restrict__ Wo,
        const float* __restrict__ W1, const float* __restrict__ W2,
        const float* __restrict__ bq, const float* __restrict__ bk,
        const float* __restrict__ bv,
        u16* __restrict__ WqkvB, u16* __restrict__ WoB,
        u16* __restrict__ W1B, u16* __restrict__ W2B,
        float* __restrict__ bqkv,
        const float* __restrict__ x, const float* __restrict__ g1,
        const float* __restrict__ b1v, u16* __restrict__ hB) {
    if (blockIdx.x < 1024) {
        int row = blockIdx.x * 4 + (threadIdx.x >> 6);
        int t = threadIdx.x & 63;
        const float* xr = x + (size_t)row * E_;
        float v[16];
        float sum = 0.f, ss = 0.f;
#pragma unroll
        for (int c = 0; c < 4; c++) {
            float4 f = *(const float4*)&xr[c * 256 + t * 4];
            v[c * 4 + 0] = f.x; v[c * 4 + 1] = f.y; v[c * 4 + 2] = f.z; v[c * 4 + 3] = f.w;
            sum += f.x + f.y + f.z + f.w;
            ss += f.x * f.x + f.y * f.y + f.z * f.z + f.w * f.w;
        }
#pragma unroll
        for (int d = 32; d; d >>= 1) {
            sum += __shfl_xor(sum, d);
            ss  += __shfl_xor(ss, d);
        }
        float mu = sum * (1.f / E_);
        float var = ss * (1.f / E_) - mu * mu;
        float rs = rsqrtf(var + 1e-5f);
#pragma unroll
        for (int c = 0; c < 4; c++) {
            int idx = c * 256 + t * 4;
            float4 g4 = *(const float4*)&g1[idx];
            float4 b4 = *(const float4*)&b1v[idx];
            ushort4 o;
            o.x = f2b((v[c * 4 + 0] - mu) * rs * g4.x + b4.x);
            o.y = f2b((v[c * 4 + 1] - mu) * rs * g4.y + b4.y);
            o.z = f2b((v[c * 4 + 2] - mu) * rs * g4.z + b4.z);
            o.w = f2b((v[c * 4 + 3] - mu) * rs * g4.w + b4.w);
            *(ushort4*)&hB[(size_t)row * E_ + idx] = o;
        }
        return;
    }
    int i = (blockIdx.x - 1024) * 256 + threadIdx.x;
    if (i >= 3146496) return;
    if (i >= 3145728) {             // biases (fp32 copy)
        int j = i - 3145728;        // 0..767
        const float* s = (j < 256) ? bq : (j < 512) ? bk : bv;
        int jj = j & 255;
        *(float4*)&bqkv[j * 4] = *(const float4*)&s[jj * 4];
        return;
    }
    const float* src; u16* dst; int j;
    if (i < 786432) {
        src = (i < 262144) ? Wq : (i < 524288) ? Wk : Wv;
        j = i & 262143;
        dst = WqkvB + (i >> 18) * (E_ * E_);
    } else if (i < 1048576) { j = i - 786432;  src = Wo; dst = WoB; }
    else if (i < 2097152)   { j = i - 1048576; src = W1; dst = W1B; }
    else                    { j = i - 2097152; src = W2; dst = W2B; }
    float4 f = *(const float4*)&src[j * 4];
    ushort4 o;
    o.x = f2b(f.x); o.y = f2b(f.y); o.z = f2b(f.z); o.w = f2b(f.w);
    *(ushort4*)&dst[j * 4] = o;
}

// ---------------- LayerNorm: 1 wave per row of 1024 ----------------
__global__ __launch_bounds__(64) void ln_fwd(u16* __restrict__ out, const float* __restrict__ x,
                                             const float* __restrict__ g, const float* __restrict__ bta) {
    int row = blockIdx.x;
    int t = threadIdx.x;
    const float* xr = x + (size_t)row * E_;
    float v[16];
    float sum = 0.f, ss = 0.f;
#pragma unroll
    for (int c = 0; c < 4; c++) {
        float4 f = *(const float4*)&xr[c * 256 + t * 4];
        v[c * 4 + 0] = f.x; v[c * 4 + 1] = f.y; v[c * 4 + 2] = f.z; v[c * 4 + 3] = f.w;
        sum += f.x + f.y + f.z + f.w;
        ss += f.x * f.x + f.y * f.y + f.z * f.z + f.w * f.w;
    }
#pragma unroll
    for (int d = 32; d; d >>= 1) {
        sum += __shfl_xor(sum, d);
        ss  += __shfl_xor(ss, d);
    }
    float mu = sum * (1.f / E_);
    float var = ss * (1.f / E_) - mu * mu;
    float rs = rsqrtf(var + 1e-5f);
#pragma unroll
    for (int c = 0; c < 4; c++) {
        int idx = c * 256 + t * 4;
        float4 g4 = *(const float4*)&g[idx];
        float4 b4 = *(const float4*)&bta[idx];
        ushort4 o;
        o.x = f2b((v[c * 4 + 0] - mu) * rs * g4.x + b4.x);
        o.y = f2b((v[c * 4 + 1] - mu) * rs * g4.y + b4.y);
        o.z = f2b((v[c * 4 + 2] - mu) * rs * g4.z + b4.z);
        o.w = f2b((v[c * 4 + 3] - mu) * rs * g4.w + b4.w);
        *(ushort4*)&out[(size_t)row * E_ + idx] = o;
    }
}

// ---------------- bf16 MFMA GEMM, double-buffered global_load_lds pipeline ----------------
// C[M,N] = A[M,K] * Bt[N,K]^T. BMx128 tile (BM=128 or 64), 256 thr (2x2 waves), BK=32.
// BM=64 gives 2x the grid for N=1024 shapes (FF2/out-proj): 2 blocks/CU so other
// blocks' waves cover the barrier's vmcnt(0) drain (m102: 1 blk/CU plateaus ~320TF).
template<int BM>
__global__ __launch_bounds__(256) void gemm_bt(
        const u16* __restrict__ A, const u16* __restrict__ Bt,
        const float* __restrict__ bias, const float* __restrict__ residual,
        float* __restrict__ outF, u16* __restrict__ outB, u16* __restrict__ outVt,
        int M, int N, int K, int relu, int qkvmode) {
    constexpr int MT = BM / 32;          // m-frags per wave (128->4, 64->2)
    __shared__ __align__(16) u16 As[2][BM * 32];
    __shared__ __align__(16) u16 Bs[2][128 * 32];
    int tid = threadIdx.x;
    int m0 = blockIdx.y * BM, n0 = blockIdx.x * 128;
    int wave = tid >> 6, lane = tid & 63;
    int wm = wave & 1, wn = wave >> 1;
    int r16 = lane & 15, kg = lane >> 4;

    // staging: A covers BM rows in BM/16 gl16 calls (wave does BM/64 of them);
    // B covers 128 rows in 8 calls (2 per wave). lane offset = lane*16B.
    const u16* gA = A + (size_t)(m0 + wave * (BM / 4) + (lane >> 2)) * K + (lane & 3) * 8;
    const u16* gB = Bt + (size_t)(n0 + wave * 32 + (lane >> 2)) * K + (lane & 3) * 8;
    size_t row16 = (size_t)16 * K;
    int aoff = wave * (BM / 4) * 32;
    int boff = wave * 1024;

    f32x4 acc[MT][4] = {};

    const int nk = K >> 5;
    // prologue: prefetch k-step 0 into buffer 0
    gl16(gA, As[0] + aoff);
    if (BM == 128) gl16(gA + row16, As[0] + aoff + 512);
    gl16(gB, Bs[0] + boff);
    gl16(gB + row16, Bs[0] + boff + 512);

    for (int ks = 0; ks < nk; ks++) {
        int cur = ks & 1;
        __syncthreads();                 // drains own gl16s (vmcnt0) + barrier
        if (ks + 1 < nk) {               // prefetch next step into other buffer
            int k1 = (ks + 1) << 5;
            int nxt = cur ^ 1;
            gl16(gA + k1, As[nxt] + aoff);
            if (BM == 128) gl16(gA + k1 + row16, As[nxt] + aoff + 512);
            gl16(gB + k1, Bs[nxt] + boff);
            gl16(gB + k1 + row16, Bs[nxt] + boff + 512);
        }

        bf16x8 af[MT], bfr[4];
#pragma unroll
        for (int mt = 0; mt < MT; mt++)
            af[mt] = *(const bf16x8*)&As[cur][(wm * (BM / 2) + mt * 16 + r16) * 32 + kg * 8];
#pragma unroll
        for (int nt = 0; nt < 4; nt++)
            bfr[nt] = *(const bf16x8*)&Bs[cur][(wn * 64 + nt * 16 + r16) * 32 + kg * 8];
#pragma unroll
        for (int mt = 0; mt < MT; mt++)
#pragma unroll
            for (int nt = 0; nt < 4; nt++)
                acc[mt][nt] = __builtin_amdgcn_mfma_f32_16x16x32_bf16(af[mt], bfr[nt], acc[mt][nt], 0, 0, 0);
    }

#pragma unroll
    for (int mt = 0; mt < MT; mt++) {
#pragma unroll
        for (int nt = 0; nt < 4; nt++) {
            int gm = m0 + wm * (BM / 2) + mt * 16 + kg * 4;
            int gn = n0 + wn * 64 + nt * 16 + r16;
            float bv = bias[gn];
            if (qkvmode) {
                if (gn < 2048) {
                    float scl = (gn < 1024) ? 0.125f : 1.0f;
#pragma unroll
                    for (int r = 0; r < 4; r++)
                        outB[(size_t)(gm + r) * 2048 + gn] = f2b((acc[mt][nt][r] + bv) * scl);
                } else {
                    int bq_ = gm >> 11, tq = gm & 2047, d = gn - 2048;
                    ushort4 ov;
                    ov.x = f2b(acc[mt][nt][0] + bv);
                    ov.y = f2b(acc[mt][nt][1] + bv);
                    ov.z = f2b(acc[mt][nt][2] + bv);
                    ov.w = f2b(acc[mt][nt][3] + bv);
                    *(ushort4*)&outVt[((size_t)(bq_ * 1024 + d)) * 2048 + tq] = ov;
                }
            } else {
#pragma unroll
                for (int r = 0; r < 4; r++) {
                    float v = acc[mt][nt][r] + bv;
                    size_t off = (size_t)(gm + r) * N + gn;
                    if (residual) v += residual[off];
                    if (relu) v = fmaxf(v, 0.f);
                    if (outF) outF[off] = v;
                    else outB[off] = f2b(v);
                }
            }
        }
    }
}

// ---------------- MFMA flash attention (bf16, causal) ----------------
// grid = 1024; bz = qt*32 + b*16 + h  (qt in HIGH bits -> same-CU blocks get mixed qt).
#define AST 72   // 144B row stride: 36 dwords === 4 mod 32 -> conflict-free b128
__global__ __launch_bounds__(256) void attn_mfma(
        const u16* __restrict__ qk, const u16* __restrict__ vt,
        u16* __restrict__ out) {
    __shared__ __align__(16) u16 Ks[64 * AST];     // K[key][d]
    __shared__ __align__(16) u16 Vs[64 * AST];     // Vt[d][key]
    __shared__ __align__(16) u16 Ps[4][16 * AST];  // per-wave P[q][key]

    int bz = blockIdx.x;
    int h  = bz & 15;
    int b  = (bz >> 4) & 1;
    int qt = bz >> 5;

    int tid = threadIdx.x;
    int w = tid >> 6, lane = tid & 63;
    int g = lane >> 4, l16 = lane & 15;

    int qrow = qt * 64 + w * 16 + l16;
    bf16x8 qf[2];
    qf[0] = *(const bf16x8*)&qk[(size_t)(b * T_ + qrow) * 2048 + h * 64 + g * 8];
    qf[1] = *(const bf16x8*)&qk[(size_t)(b * T_ + qrow) * 2048 + h * 64 + 32 + g * 8];

    f32x4 o[4] = {};
    float mrun[4] = {-INFINITY, -INFINITY, -INFINITY, -INFINITY};
    float lrun[4] = {0.f, 0.f, 0.f, 0.f};

    int r1 = tid >> 3, col1 = (tid & 7) * 8;
    int r2 = (tid + 256) >> 3, col2 = ((tid + 256) & 7) * 8;
    const u16* gK = qk + (size_t)(b * T_) * 2048 + 1024 + h * 64;
    const u16* gV = vt + (size_t)(b * 1024 + h * 64) * 2048;

    uint4 kr1, kr2, vr1, vr2;
    {
        kr1 = *(const uint4*)&gK[(size_t)r1 * 2048 + col1];
        kr2 = *(const uint4*)&gK[(size_t)r2 * 2048 + col2];
        vr1 = *(const uint4*)&gV[(size_t)r1 * 2048 + col1];
        vr2 = *(const uint4*)&gV[(size_t)r2 * 2048 + col2];
    }

    for (int t = 0; t <= qt; t++) {
        int j0 = t * 64;
        __syncthreads();                      // (A) prev tile fully consumed
        *(uint4*)&Ks[r1 * AST + col1] = kr1;
        *(uint4*)&Ks[r2 * AST + col2] = kr2;
        *(uint4*)&Vs[r1 * AST + col1] = vr1;
        *(uint4*)&Vs[r2 * AST + col2] = vr2;
        __syncthreads();                      // (B) LDS valid
        if (t < qt) {                         // prefetch next tile AFTER (B)
            int j1 = j0 + 64;
            kr1 = *(const uint4*)&gK[(size_t)(j1 + r1) * 2048 + col1];
            kr2 = *(const uint4*)&gK[(size_t)(j1 + r2) * 2048 + col2];
            vr1 = *(const uint4*)&gV[(size_t)r1 * 2048 + j1 + col1];
            vr2 = *(const uint4*)&gV[(size_t)r2 * 2048 + j1 + col2];
        }

        f32x4 s[4] = {};
#pragma unroll
        for (int nt = 0; nt < 4; nt++) {
            bf16x8 k0 = *(const bf16x8*)&Ks[(nt * 16 + l16) * AST + g * 8];
            bf16x8 k1 = *(const bf16x8*)&Ks[(nt * 16 + l16) * AST + 32 + g * 8];
            s[nt] = __builtin_amdgcn_mfma_f32_16x16x32_bf16(qf[0], k0, s[nt], 0, 0, 0);
            s[nt] = __builtin_amdgcn_mfma_f32_16x16x32_bf16(qf[1], k1, s[nt], 0, 0, 0);
        }

        if (t == qt) {
#pragma unroll
            for (int nt = 0; nt < 4; nt++) {
                int key = j0 + nt * 16 + l16;
#pragma unroll
                for (int r = 0; r < 4; r++) {
                    int q = qt * 64 + w * 16 + g * 4 + r;
                    if (key > q) s[nt][r] = -INFINITY;
                }
            }
        }

        float tm[4];
#pragma unroll
        for (int r = 0; r < 4; r++)
            tm[r] = fmaxf(fmaxf(s[0][r], s[1][r]), fmaxf(s[2][r], s[3][r]));
#pragma unroll
        for (int x = 1; x <= 8; x <<= 1)
#pragma unroll
            for (int r = 0; r < 4; r++)
                tm[r] = fmaxf(tm[r], __shfl_xor(tm[r], x));

        float al[4];
#pragma unroll
        for (int r = 0; r < 4; r++) {
            float mn = fmaxf(mrun[r], tm[r]);
            al[r] = __expf(mrun[r] - mn);
            mrun[r] = mn;
        }

        float rs[4] = {0.f, 0.f, 0.f, 0.f};
#pragma unroll
        for (int nt = 0; nt < 4; nt++)
#pragma unroll
            for (int r = 0; r < 4; r++) {
                float p = __expf(s[nt][r] - mrun[r]);
                rs[r] += p;
                Ps[w][(g * 4 + r) * AST + nt * 16 + l16] = f2b(p);
            }
#pragma unroll
        for (int x = 1; x <= 8; x <<= 1)
#pragma unroll
            for (int r = 0; r < 4; r++)
                rs[r] += __shfl_xor(rs[r], x);
#pragma unroll
        for (int r = 0; r < 4; r++)
            lrun[r] = lrun[r] * al[r] + rs[r];

#pragma unroll
        for (int nt = 0; nt < 4; nt++)
#pragma unroll
            for (int r = 0; r < 4; r++)
                o[nt][r] *= al[r];

#pragma unroll
        for (int kf = 0; kf < 2; kf++) {
            bf16x8 pf = *(const bf16x8*)&Ps[w][l16 * AST + kf * 32 + g * 8];
#pragma unroll
            for (int nt = 0; nt < 4; nt++) {
                bf16x8 vf = *(const bf16x8*)&Vs[(nt * 16 + l16) * AST + kf * 32 + g * 8];
                o[nt] = __builtin_amdgcn_mfma_f32_16x16x32_bf16(pf, vf, o[nt], 0, 0, 0);
            }
        }
    }

    float inv[4];
#pragma unroll
    for (int r = 0; r < 4; r++) inv[r] = 1.f / lrun[r];
    int qg = qt * 64 + w * 16 + g * 4;
#pragma unroll
    for (int nt = 0; nt < 4; nt++)
#pragma unroll
        for (int r = 0; r < 4; r++)
            out[(size_t)(b * T_ + qg + r) * E_ + h * 64 + nt * 16 + l16] =
                f2b(o[nt][r] * inv[r]);
}

extern "C" void kernel_launch(void* const* d_in, const int* in_sizes, int n_in,
                              void* d_out, int out_size, void* d_ws, size_t ws_size,
                              hipStream_t stream) {
    const float* x    = (const float*)d_in[0];
    const float* Wq   = (const float*)d_in[1];
    const float* bq   = (const float*)d_in[2];
    const float* Wk   = (const float*)d_in[3];
    const float* bk   = (const float*)d_in[4];
    const float* Wv   = (const float*)d_in[5];
    const float* bv   = (const float*)d_in[6];
    const float* Wo   = (const float*)d_in[7];
    const float* bo   = (const float*)d_in[8];
    const float* W1   = (const float*)d_in[9];
    const float* b1   = (const float*)d_in[10];
    const float* W2   = (const float*)d_in[11];
    const float* b2   = (const float*)d_in[12];
    const float* ln1g = (const float*)d_in[13];
    const float* ln1b = (const float*)d_in[14];
    const float* ln2g = (const float*)d_in[15];
    const float* ln2b = (const float*)d_in[16];

    char* ws = (char*)d_ws;
    size_t off = 0;
    auto alloc = [&](size_t bytes) { char* p = ws + off; off += (bytes + 255) & ~(size_t)255; return p; };

    u16*   hB    = (u16*)  alloc((size_t)M_ * E_ * 2);        // LN1 out bf16
    u16*   WqkvB = (u16*)  alloc((size_t)3 * E_ * E_ * 2);    // packed q,k,v weights bf16
    u16*   WoB   = (u16*)  alloc((size_t)E_ * E_ * 2);
    u16*   W1B   = (u16*)  alloc((size_t)FF_ * E_ * 2);
    u16*   W2B   = (u16*)  alloc((size_t)E_ * FF_ * 2);
    float* bqkv  = (float*)alloc(3 * E_ * 4);
    u16*   qkB   = (u16*)  alloc((size_t)M_ * 2 * E_ * 2);    // bf16 [M,2048], Q prescaled
    u16*   vtG   = (u16*)  alloc((size_t)M_ * E_ * 2);        // bf16 V^T [B*1024, 2048]
    u16*   attnB = (u16*)  alloc((size_t)M_ * E_ * 2);        // attention out bf16
    float* x2    = (float*)alloc((size_t)M_ * E_ * 4);        // after out-proj + residual
    u16*   h2B   = (u16*)  alloc((size_t)M_ * E_ * 2);        // LN2 out bf16
    u16*   rB    = (u16*)  alloc((size_t)M_ * FF_ * 2);       // relu(ff1) bf16

    // fused weight/bias conversion + LN1 (one launch)
    cvt_ln<<<1024 + 12291, 256, 0, stream>>>(Wq, Wk, Wv, Wo, W1, W2, bq, bk, bv,
                                             WqkvB, WoB, W1B, W2B, bqkv,
                                             x, ln1g, ln1b, hB);

    // fused QKV projection: [4096,1024] x [3072,1024]^T  (768 blocks, 3/CU)
    gemm_bt<128><<<dim3(3 * E_ / 128, M_ / 128), 256, 0, stream>>>(
        hB, WqkvB, bqkv, nullptr, nullptr, qkB, vtG, M_, 3 * E_, E_, 0, 1);

    // flash attention
    attn_mfma<<<B_ * H_ * (T_ / 64), 256, 0, stream>>>(qkB, vtG, attnB);

    // out projection + residual: x2 = x + attn @ Wo^T + bo  (512 blocks, 2/CU)
    gemm_bt<64><<<dim3(E_ / 128, M_ / 64), 256, 0, stream>>>(
        attnB, WoB, bo, x, x2, nullptr, nullptr, M_, E_, E_, 0, 0);

    // LN2
    ln_fwd<<<M_, 64, 0, stream>>>(h2B, x2, ln2g, ln2b);

    // FF1 + relu -> bf16  (1024 blocks, 4/CU)
    gemm_bt<128><<<dim3(FF_ / 128, M_ / 128), 256, 0, stream>>>(
        h2B, W1B, b1, nullptr, nullptr, rB, nullptr, M_, FF_, E_, 1, 0);

    // FF2 + residual -> out  (512 blocks, 2/CU)
    gemm_bt<64><<<dim3(E_ / 128, M_ / 64), 256, 0, stream>>>(
        rB, W2B, b2, x2, (float*)d_out, nullptr, nullptr, M_, E_, FF_, 0, 0);
}